// Round 4
// baseline (67.695 us; speedup 1.0000x reference)
//
#include <hip/hip_runtime.h>
#include <math.h>

// PROBE ROUND: same kernel as round 3, launched 4x back-to-back (idempotent,
// deterministic) to separate fixed replay overhead from kernel-body time:
//   round3: floor + 1*body = 19.8 us;  this: floor + 4*body.
//
// RoI pooling: fm [2,56,56,256] f32, rois [2,48,4] f32 (x, y_max, w, h),
// out [2,48,7,7,256] f32. One WAVE per output bin; lane l holds channels
// 4l..4l+3 as float4. Geometry on SALU via readfirstlane.

#define NB 2
#define NR 48
#define FH 56
#define FW 56
#define NC 256
#define PH 7
#define PW 7
#define NBINS (NB * NR * PH * PW)   // 4704 = 1176 blocks * 4 waves exactly

__global__ __launch_bounds__(256) void roi_pool_kernel(
    const float4* __restrict__ fm4, const float* __restrict__ rois,
    float4* __restrict__ out4) {
  const int lane = threadIdx.x & 63;          // channel group (4 ch each)
  int bin = __builtin_amdgcn_readfirstlane(blockIdx.x * 4 + (threadIdx.x >> 6));
  const int obin = bin;

  const int j = bin % PW; bin /= PW;
  const int i = bin % PH; bin /= PH;
  const int r = bin % NR;
  const int b = bin / NR;

  const float* roi = rois + (b * NR + r) * 4;
  const float x = roi[0], y = roi[1], w = roi[2], h = roi[3];

  // Match JAX reference fp32 arithmetic + trunc-to-int32 exactly.
  const int w_start = (int)(56.0f * x);
  const int w_end   = (int)(56.0f * (x + w));
  const int h_start = (int)(56.0f * (1.0f - y));
  const int h_end   = (int)(56.0f * (1.0f - y + h));
  const int rh = h_end - h_start;
  const int rw = w_end - w_start;
  const int h_step = rh / PH;
  const int w_step = rw / PW;

  const int r0 = h_start + i * h_step;
  const int r1 = (i == PH - 1) ? (h_start + rh) : (r0 + h_step);
  const int c0 = w_start + j * w_step;
  const int c1 = (j == PW - 1) ? (w_start + rw) : (c0 + w_step);

  float4 m = make_float4(-INFINITY, -INFINITY, -INFINITY, -INFINITY);
  const float4* base = fm4 + ((size_t)(b * FH) * FW) * 64 + lane;
  for (int yy = r0; yy < r1; ++yy) {
    const float4* rowp = base + (size_t)(yy * FW) * 64;
    for (int xx = c0; xx < c1; ++xx) {
      float4 v = rowp[(size_t)xx * 64];
      m.x = fmaxf(m.x, v.x);
      m.y = fmaxf(m.y, v.y);
      m.z = fmaxf(m.z, v.z);
      m.w = fmaxf(m.w, v.w);
    }
  }

  out4[(size_t)obin * 64 + lane] = m;
}

extern "C" void kernel_launch(void* const* d_in, const int* in_sizes, int n_in,
                              void* d_out, int out_size, void* d_ws, size_t ws_size,
                              hipStream_t stream) {
  const float4* fm4 = (const float4*)d_in[0];
  const float* rois = (const float*)d_in[1];
  float4* out4 = (float4*)d_out;
  // 4 identical launches: body multiplier for the overhead-vs-body probe.
  roi_pool_kernel<<<NBINS / 4, 256, 0, stream>>>(fm4, rois, out4);
  roi_pool_kernel<<<NBINS / 4, 256, 0, stream>>>(fm4, rois, out4);
  roi_pool_kernel<<<NBINS / 4, 256, 0, stream>>>(fm4, rois, out4);
  roi_pool_kernel<<<NBINS / 4, 256, 0, stream>>>(fm4, rois, out4);
}

// Round 6
// 15.288 us; speedup vs baseline: 4.4279x; 4.4279x over previous
//
#include <hip/hip_runtime.h>
#include <math.h>

// RoI pooling: fm [2,56,56,256] f32, rois [2,48,4] f32 (x, y_max, w, h),
// out [2,48,7,7,256] f32.
//
// One WAVE per output bin; lane l holds channels 4l..4l+3 as a float4
// (1 KB/wave coalesced loads). Geometry on SALU via readfirstlane.
//
// Latency fix: bin extents are in [2,10] per dim (step = extent//7 in [2,4],
// last bin absorbs remainder <= 6). Pool in clamped compile-time 4x4 chunks
// (duplicate reads harmless under max): 16 independent loads issue together,
// ONE vmcnt wait per chunk (~220cy L2 latency amortized 16x). Common bins:
// 1 chunk; worst 10x10 corner bin: 9 chunks vs 100 serial load-waits.
//
// ROUND-5 BUG FIXED: extent can be 10 (not 9); old CW=9 clamp dropped the
// 10th column. Both dims now chunk-looped with clamping, any extent correct.

#define NB 2
#define NR 48
#define FH 56
#define FW 56
#define PH 7
#define PW 7
#define NBINS (NB * NR * PH * PW)   // 4704 = 1176 blocks * 4 waves exactly

__device__ inline void fm4max(float4& m, const float4 v) {
  m.x = fmaxf(m.x, v.x);
  m.y = fmaxf(m.y, v.y);
  m.z = fmaxf(m.z, v.z);
  m.w = fmaxf(m.w, v.w);
}

// Pool rows [r0, r0+Eh) x cols [c0, c0+Ew) in clamped CHxCW chunks.
// Eh, Ew are wave-uniform; all v[][] indices compile-time -> registers.
template <int CH, int CW>
__device__ inline float4 pool_bin(const float4* __restrict__ base,
                                  int r0, int Eh, int c0, int Ew) {
  float4 m0 = make_float4(-INFINITY, -INFINITY, -INFINITY, -INFINITY);
  float4 m1 = m0;
  for (int rc = 0; rc < Eh; rc += CH) {
    for (int cc = 0; cc < Ew; cc += CW) {
      float4 v[CH][CW];
#pragma unroll
      for (int k = 0; k < CH; ++k) {
        int rr = rc + k;
        rr = (rr < Eh) ? rr : (Eh - 1);       // clamp: re-read last row
        const float4* rowp = base + (size_t)((r0 + rr) * FW) * 64;
#pragma unroll
        for (int q = 0; q < CW; ++q) {
          int c = cc + q;
          c = (c < Ew) ? c : (Ew - 1);        // clamp: re-read last col
          v[k][q] = rowp[(size_t)(c0 + c) * 64];
        }
      }
#pragma unroll
      for (int k = 0; k < CH; ++k) {
#pragma unroll
        for (int q = 0; q < CW; ++q) {
          if (((k * CW + q) & 1) == 0) fm4max(m0, v[k][q]);
          else                         fm4max(m1, v[k][q]);
        }
      }
    }
  }
  fm4max(m0, m1);
  return m0;
}

__global__ __launch_bounds__(256) void roi_pool_kernel(
    const float4* __restrict__ fm4, const float* __restrict__ rois,
    float4* __restrict__ out4) {
  const int lane = threadIdx.x & 63;          // channel group (4 ch each)
  int bin = __builtin_amdgcn_readfirstlane(blockIdx.x * 4 + (threadIdx.x >> 6));
  const int obin = bin;

  const int j = bin % PW; bin /= PW;
  const int i = bin % PH; bin /= PH;
  const int r = bin % NR;
  const int b = bin / NR;

  const float* roi = rois + (b * NR + r) * 4;
  const float x = roi[0], y = roi[1], w = roi[2], h = roi[3];

  // Match JAX reference fp32 arithmetic + trunc-to-int32 exactly.
  const int w_start = (int)(56.0f * x);
  const int w_end   = (int)(56.0f * (x + w));
  const int h_start = (int)(56.0f * (1.0f - y));
  const int h_end   = (int)(56.0f * (1.0f - y + h));
  const int rh = h_end - h_start;
  const int rw = w_end - w_start;
  const int h_step = rh / PH;
  const int w_step = rw / PW;

  const int r0 = h_start + i * h_step;
  const int r1 = (i == PH - 1) ? (h_start + rh) : (r0 + h_step);
  const int c0 = w_start + j * w_step;
  const int c1 = (j == PW - 1) ? (w_start + rw) : (c0 + w_step);

  const int Eh = r1 - r0;                     // in [2, 10]
  const int Ew = c1 - c0;                     // in [2, 10]

  const float4* base = fm4 + ((size_t)(b * FH) * FW) * 64 + lane;
  const float4 m = pool_bin<4, 4>(base, r0, Eh, c0, Ew);

  out4[(size_t)obin * 64 + lane] = m;
}

extern "C" void kernel_launch(void* const* d_in, const int* in_sizes, int n_in,
                              void* d_out, int out_size, void* d_ws, size_t ws_size,
                              hipStream_t stream) {
  const float4* fm4 = (const float4*)d_in[0];
  const float* rois = (const float*)d_in[1];
  float4* out4 = (float4*)d_out;
  roi_pool_kernel<<<NBINS / 4, 256, 0, stream>>>(fm4, rois, out4);
}